// Round 5
// baseline (279.055 us; speedup 1.0000x reference)
//
#include <hip/hip_runtime.h>
#include <math.h>

#define NUM_EMB 1024
#define EMB_DIM 256
#define N_ROWS  65536
#define HW      1024
#define QUANT_OFF 1
#define IDX_OFF   (1 + 16777216)
#define LDA 264   // halfs per A-row: 528B stride -> clean b128 access, 2-way banks (free)
#define KSTR 132  // key-scratch row stride in dwords

typedef unsigned int uint;
typedef _Float16 f16x8 __attribute__((ext_vector_type(8)));
typedef float    f32x4 __attribute__((ext_vector_type(4)));

__device__ __forceinline__ uint umin2(uint a, uint b) { return a < b ? a : b; }
__device__ __forceinline__ uint umax2(uint a, uint b) { return a > b ? a : b; }

// median of 3 == 2nd-largest of 3; single VALU op on gfx9+
__device__ __forceinline__ uint umed3(uint a, uint b, uint c) {
  uint d;
  asm("v_med3_u32 %0, %1, %2, %3" : "=v"(d) : "v"(a), "v"(b), "v"(c));
  return d;
}

// ---- kernel 1: normalize codebook -> wn (f32), wh2 (f16, MFMA-B-swizzled), rinv (f64) ----
// wh2 halfs layout: [chunk(4)][ks(8)][q(4)][code-in-chunk(256)][e(8)], d = ks*32+q*8+e.
// Equivalently: slab s = chunk*8+ks at offset s*8192.
__global__ __launch_bounds__(256)
void k_norm_w(const float* __restrict__ w, float* __restrict__ wn,
              _Float16* __restrict__ wh2, double* __restrict__ rinv) {
  const int k = blockIdx.x, t = threadIdx.x;
  const float v = w[(size_t)k * EMB_DIM + t];
  double s = (double)v * (double)v;
  for (int o = 32; o; o >>= 1) s += __shfl_down(s, o);
  __shared__ double ps[4];
  if ((t & 63) == 0) ps[t >> 6] = s;
  __syncthreads();
  const double tot = ps[0] + ps[1] + ps[2] + ps[3];
  const float nv = v / fmaxf((float)sqrt(tot), 1e-12f);
  wn[(size_t)k * EMB_DIM + t] = nv;
  const int chunk = k >> 8, cc = k & 255;
  const int ks = t >> 5, q = (t >> 3) & 3, e = t & 7;
  wh2[(size_t)chunk * 65536 + ks * 8192 + q * 2048 + cc * 8 + e] = (_Float16)nv;
  if (t == 0) rinv[k] = 1.0 / fmax(sqrt(tot), 1e-12);
}

// ---- fused kernel: MFMA top-4 + fp64 recheck + loss + quant ----
// 2048 blocks x 256 thr, 32 rows/block (8 blocks/CU queued -> phase-skewed rotation).
// B streamed L2->VGPR with depth-2 prefetch (3-buffer static rotation); A in LDS;
// recheck re-reads x from L3; quant stores direct (no LDS transpose).
__global__ __launch_bounds__(256, 4)
void k_fused(const float* __restrict__ x, const _Float16* __restrict__ wh2,
             const float* __restrict__ w, const float* __restrict__ wn,
             const double* __restrict__ rinv, float* __restrict__ out) {
  __shared__ __align__(16) _Float16 As[32 * LDA];   // 16896 B; reused: keys / red
  __shared__ uint4 cand_s[32];
  __shared__ int   cw_s[32];
  const int t = threadIdx.x;
  const int blk = blockIdx.x;
  const int b = blk >> 5;
  const int hw0 = (blk & 31) * 32;

  const int lane = t & 63;
  const int q = lane >> 4;
  const int l15 = lane & 15;
  const int w4id = t >> 6;

  // per-lane B element offsets (halfs) within a ks-slab of wh2
  const int bvo0 = q * 2048 + (w4id * 64 +  0 + l15) * 8;
  const int bvo1 = q * 2048 + (w4id * 64 + 16 + l15) * 8;
  const int bvo2 = q * 2048 + (w4id * 64 + 32 + l15) * 8;
  const int bvo3 = q * 2048 + (w4id * 64 + 48 + l15) * 8;

#define LOADB(buf, s)                                       \
  { const _Float16* ksb_ = wh2 + (size_t)(s) * 8192;        \
    buf[0] = *(const f16x8*)&ksb_[bvo0];                    \
    buf[1] = *(const f16x8*)&ksb_[bvo1];                    \
    buf[2] = *(const f16x8*)&ksb_[bvo2];                    \
    buf[3] = *(const f16x8*)&ksb_[bvo3]; }

  f16x8 bb[3][4];
  LOADB(bb[0], 0);   // prefetch steps 0,1 (overlap with A staging)
  LOADB(bb[1], 1);

  // stage A: x[b, d, hw0+r] f32 -> As[r][d] f16, packed 8 halfs per ds_write_b128
  const int r_own = t & 31;   // row this thread owns (staging, recheck, quant)
  const int ph = t >> 5;      // d-slice: ph*32 .. ph*32+31
  {
    const float* xb = x + (size_t)b * (EMB_DIM * HW) + hw0 + r_own;
#pragma unroll
    for (int jp = 0; jp < 4; ++jp) {
      const int d0 = ph * 32 + jp * 8;
      f16x8 v;
#pragma unroll
      for (int e = 0; e < 8; ++e)
        v[e] = (_Float16)xb[(size_t)(d0 + e) * HW];
      *(f16x8*)&As[r_own * LDA + d0] = v;
    }
  }
  __syncthreads();   // A tile staged

  uint t1[8], t2[8];
#pragma unroll
  for (int i = 0; i < 8; ++i) { t1[i] = 0u; t2[i] = 0u; }

#pragma unroll
  for (int c4 = 0; c4 < 4; ++c4) {
    f32x4 acc[2][4];
#pragma unroll
    for (int rt = 0; rt < 2; ++rt)
#pragma unroll
      for (int ct = 0; ct < 4; ++ct) acc[rt][ct] = (f32x4)0.f;

#pragma unroll
    for (int ks = 0; ks < 8; ++ks) {
      const int s = c4 * 8 + ks;          // compile-time after unroll
      if (s + 2 < 32) { LOADB(bb[(s + 2) % 3], s + 2); }   // depth-2 prefetch

      const f16x8 a0 = *(const f16x8*)&As[( 0 + l15) * LDA + ks * 32 + q * 8];
      const f16x8 a1 = *(const f16x8*)&As[(16 + l15) * LDA + ks * 32 + q * 8];

      __builtin_amdgcn_s_setprio(1);
#pragma unroll
      for (int ct = 0; ct < 4; ++ct) {
        acc[0][ct] = __builtin_amdgcn_mfma_f32_16x16x32_f16(a0, bb[s % 3][ct], acc[0][ct], 0, 0, 0);
        acc[1][ct] = __builtin_amdgcn_mfma_f32_16x16x32_f16(a1, bb[s % 3][ct], acc[1][ct], 0, 0, 0);
      }
      __builtin_amdgcn_s_setprio(0);
    }

    // merge into per-(lane,slot) top-2 packed keys (score hi-bits | idx)
#pragma unroll
    for (int ct = 0; ct < 4; ++ct) {
      const uint idxv = (uint)(c4 * 256 + w4id * 64 + ct * 16 + l15);
#pragma unroll
      for (int rt = 0; rt < 2; ++rt)
#pragma unroll
        for (int r = 0; r < 4; ++r) {
          const float v = fmaxf(acc[rt][ct][r], 0.0f);
          const uint key = (__float_as_uint(v) & 0xFFFFFC00u) | idxv;
          const int slot = rt * 4 + r;
          t2[slot] = umed3(key, t1[slot], t2[slot]);
          t1[slot] = umax2(key, t1[slot]);
        }
    }
  }
#undef LOADB

  // ---- block-level per-row top-4 (reuse A LDS as key scratch: 32 rows x KSTR dwords) ----
  __syncthreads();   // all waves done reading As
  uint* keys = (uint*)As;
#pragma unroll
  for (int slot = 0; slot < 8; ++slot) {
    const int rt = slot >> 2, r = slot & 3;
    const int row = rt * 16 + q * 4 + r;
    const int col = w4id * 32 + l15 * 2;
    keys[row * KSTR + col] = t1[slot];
    keys[row * KSTR + col + 1] = t2[slot];
  }
  __syncthreads();
  {
    const int row = t >> 3, seg = t & 7;   // 8 threads per row, 16 keys each
    uint s1 = 0, s2 = 0;
#pragma unroll
    for (int i = 0; i < 4; ++i) {
      const int ii = (i + t) & 3;
      const uint4 k4 = *(const uint4*)&keys[row * KSTR + seg * 16 + ii * 4];
      const uint kk[4] = {k4.x, k4.y, k4.z, k4.w};
#pragma unroll
      for (int e = 0; e < 4; ++e) {
        s2 = umed3(kk[e], s1, s2);
        s1 = umax2(kk[e], s1);
      }
    }
    __syncthreads();
    keys[t * 2] = s1;
    keys[t * 2 + 1] = s2;
  }
  __syncthreads();
  if (t < 32) {
    uint c0 = 0, c1 = 0, c2 = 0, c3 = 0;
#pragma unroll
    for (int i = 0; i < 16; ++i) {
      const uint k = keys[t * 16 + i];
      const uint n0 = umin2(c0, k); c0 = umax2(c0, k);
      const uint n1 = umin2(c1, n0); c1 = umax2(c1, n0);
      const uint n2 = umin2(c2, n1); c2 = umax2(c2, n1);
      c3 = umax2(c3, n2);
    }
    uint4 o; o.x = c0; o.y = c1; o.z = c2; o.w = c3;
    cand_s[t] = o;
  }
  __syncthreads();   // cand ready; keys region free for red reuse

  // ---- fp64 recheck: thread covers (r_own, 32-d slice); x re-read from L3 ----
  double* red = (double*)As;   // 256 threads x 5 doubles = 10240 B
  {
    const uint4 ck = cand_s[r_own];
    const uint cv[4] = {ck.x, ck.y, ck.z, ck.w};
    const float* xr = x + (size_t)b * (EMB_DIM * HW) + hw0 + r_own;
    float xf[32];
#pragma unroll
    for (int i = 0; i < 32; ++i)
      xf[i] = xr[(size_t)(ph * 32 + i) * HW];
    double sxx_p = 0.0;
#pragma unroll
    for (int i = 0; i < 32; ++i) sxx_p = fma((double)xf[i], (double)xf[i], sxx_p);
#pragma unroll
    for (int j = 0; j < 4; ++j) {
      const int c = (int)(cv[j] & 1023u);
      const float* wr = w + (size_t)c * EMB_DIM + ph * 32;
      double s = 0.0;
#pragma unroll
      for (int k = 0; k < 8; ++k) {
        const float4 wv = *(const float4*)&wr[k * 4];
        s = fma((double)xf[k * 4 + 0], (double)wv.x, s);
        s = fma((double)xf[k * 4 + 1], (double)wv.y, s);
        s = fma((double)xf[k * 4 + 2], (double)wv.z, s);
        s = fma((double)xf[k * 4 + 3], (double)wv.w, s);
      }
      red[t * 5 + j] = s;
    }
    red[t * 5 + 4] = sxx_p;
  }
  __syncthreads();

  // ---- per-row decision (first 32 lanes), loss reduce, idx store ----
  if (t < 32) {
    const uint4 ck = cand_s[t];
    const uint cv[4] = {ck.x, ck.y, ck.z, ck.w};
    double sj[4] = {0.0, 0.0, 0.0, 0.0};
    double sxx = 0.0;
#pragma unroll
    for (int p = 0; p < 8; ++p) {
      const int base = (p * 32 + t) * 5;
      sj[0] += red[base + 0];
      sj[1] += red[base + 1];
      sj[2] += red[base + 2];
      sj[3] += red[base + 3];
      sxx   += red[base + 4];
    }
    double qbest = -1e300; int cw = 1 << 30;
#pragma unroll
    for (int j = 0; j < 4; ++j) {
      const int c = (int)(cv[j] & 1023u);
      const double qj = sj[j] * rinv[c];
      if (qj > qbest || (qj == qbest && c < cw)) { qbest = qj; cw = c; }
    }
    const double dmin = 2.0 - 2.0 * qbest / fmax(sqrt(sxx), 1e-12);
    out[IDX_OFF + blk * 32 + t] = (float)cw;
    cw_s[t] = cw;
    double v = dmin;
    v += __shfl_down(v, 16);
    v += __shfl_down(v, 8);
    v += __shfl_down(v, 4);
    v += __shfl_down(v, 2);
    v += __shfl_down(v, 1);
    if (t == 0)
      atomicAdd(out, (float)(1.25 * v / 16777216.0));
  }
  __syncthreads();

  // ---- quant: direct coalesced stores (lane-per-row, 128B segments per instr) ----
  {
    const int cw = cw_s[r_own];
    const float* wr = wn + (size_t)cw * EMB_DIM + ph * 32;
    float* qo = out + QUANT_OFF + (size_t)b * (EMB_DIM * HW) + hw0 + r_own;
#pragma unroll
    for (int k = 0; k < 8; ++k) {
      const float4 wv = *(const float4*)&wr[k * 4];
      qo[(size_t)(ph * 32 + k * 4 + 0) * HW] = wv.x;
      qo[(size_t)(ph * 32 + k * 4 + 1) * HW] = wv.y;
      qo[(size_t)(ph * 32 + k * 4 + 2) * HW] = wv.z;
      qo[(size_t)(ph * 32 + k * 4 + 3) * HW] = wv.w;
    }
  }
}

extern "C" void kernel_launch(void* const* d_in, const int* in_sizes, int n_in,
                              void* d_out, int out_size, void* d_ws, size_t ws_size,
                              hipStream_t stream) {
  const float* x = (const float*)d_in[0];   // [64,256,32,32]
  const float* w = (const float*)d_in[1];   // [1024,256]
  float* out = (float*)d_out;               // [1 + 16777216 + 65536] f32

  char* ws = (char*)d_ws;
  float*     wn   = (float*)ws;                                // 1 MB
  _Float16*  wh2  = (_Float16*)(ws + 1048576);                 // 512 KB (swizzled)
  double*    rinv = (double*)(ws + 1048576 + 524288);          // 8 KB

  hipMemsetAsync(d_out, 0, sizeof(float), stream);   // zero loss accumulator
  hipLaunchKernelGGL(k_norm_w, dim3(NUM_EMB), dim3(256), 0, stream, w, wn, wh2, rinv);
  hipLaunchKernelGGL(k_fused, dim3(N_ROWS / 32), dim3(256), 0, stream, x, wh2, w, wn, rinv, out);
}

// Round 6
// 251.691 us; speedup vs baseline: 1.1087x; 1.1087x over previous
//
#include <hip/hip_runtime.h>
#include <math.h>

#define NUM_EMB 1024
#define EMB_DIM 256
#define N_ROWS  65536
#define HW      1024
#define QUANT_OFF 1
#define IDX_OFF   (1 + 16777216)
#define LDA 264   // halfs per A-row: 528B stride -> clean b128 access, 2-way banks (free)
#define KSTR 132  // key-scratch row stride in dwords

typedef unsigned int uint;
typedef _Float16 f16x8 __attribute__((ext_vector_type(8)));
typedef float    f32x4 __attribute__((ext_vector_type(4)));

__device__ __forceinline__ uint umin2(uint a, uint b) { return a < b ? a : b; }
__device__ __forceinline__ uint umax2(uint a, uint b) { return a > b ? a : b; }

// median of 3 == 2nd-largest of 3; single VALU op on gfx9+
__device__ __forceinline__ uint umed3(uint a, uint b, uint c) {
  uint d;
  asm("v_med3_u32 %0, %1, %2, %3" : "=v"(d) : "v"(a), "v"(b), "v"(c));
  return d;
}

// ---- kernel 1: normalize codebook -> wn (f32), wh2 (f16, MFMA-B-swizzled), rinv (f64) ----
// wh2 halfs layout: [chunk(4)][ks(8)][q(4)][code-in-chunk(256)][e(8)], d = ks*32+q*8+e.
// Equivalently: slab s = chunk*8+ks at offset s*8192.
__global__ __launch_bounds__(256)
void k_norm_w(const float* __restrict__ w, float* __restrict__ wn,
              _Float16* __restrict__ wh2, double* __restrict__ rinv) {
  const int k = blockIdx.x, t = threadIdx.x;
  const float v = w[(size_t)k * EMB_DIM + t];
  double s = (double)v * (double)v;
  for (int o = 32; o; o >>= 1) s += __shfl_down(s, o);
  __shared__ double ps[4];
  if ((t & 63) == 0) ps[t >> 6] = s;
  __syncthreads();
  const double tot = ps[0] + ps[1] + ps[2] + ps[3];
  const float nv = v / fmaxf((float)sqrt(tot), 1e-12f);
  wn[(size_t)k * EMB_DIM + t] = nv;
  const int chunk = k >> 8, cc = k & 255;
  const int ks = t >> 5, q = (t >> 3) & 3, e = t & 7;
  wh2[(size_t)chunk * 65536 + ks * 8192 + q * 2048 + cc * 8 + e] = (_Float16)nv;
  if (t == 0) rinv[k] = 1.0 / fmax(sqrt(tot), 1e-12);
}

// ---- fused kernel: MFMA top-4 + fp64 recheck + loss + quant ----
// 2048 blocks x 256 thr, 32 rows/block (8 blocks/CU queued -> phase-skewed rotation).
// B streamed L2->VGPR with depth-1 double buffer (STATIC cb = s&1 indexing -- no %3,
// rule #20: dynamic ext_vector indexing spills to scratch, round-5 regression);
// A in LDS; recheck re-reads x from L3; quant stores direct (no LDS transpose).
__global__ __launch_bounds__(256, 4)
void k_fused(const float* __restrict__ x, const _Float16* __restrict__ wh2,
             const float* __restrict__ w, const float* __restrict__ wn,
             const double* __restrict__ rinv, float* __restrict__ out) {
  __shared__ __align__(16) _Float16 As[32 * LDA];   // 16896 B; reused: keys / red
  __shared__ uint4 cand_s[32];
  __shared__ int   cw_s[32];
  const int t = threadIdx.x;
  const int blk = blockIdx.x;
  const int b = blk >> 5;
  const int hw0 = (blk & 31) * 32;

  const int lane = t & 63;
  const int q = lane >> 4;
  const int l15 = lane & 15;
  const int w4id = t >> 6;

  // per-lane B element offsets (halfs) within a ks-slab of wh2
  const int bvo0 = q * 2048 + (w4id * 64 +  0 + l15) * 8;
  const int bvo1 = q * 2048 + (w4id * 64 + 16 + l15) * 8;
  const int bvo2 = q * 2048 + (w4id * 64 + 32 + l15) * 8;
  const int bvo3 = q * 2048 + (w4id * 64 + 48 + l15) * 8;

#define LOADB(buf, s)                                       \
  { const _Float16* ksb_ = wh2 + (size_t)(s) * 8192;        \
    buf[0] = *(const f16x8*)&ksb_[bvo0];                    \
    buf[1] = *(const f16x8*)&ksb_[bvo1];                    \
    buf[2] = *(const f16x8*)&ksb_[bvo2];                    \
    buf[3] = *(const f16x8*)&ksb_[bvo3]; }

  f16x8 bb[2][4];
  LOADB(bb[0], 0);   // prefetch first B step (overlaps A staging)

  // stage A: x[b, d, hw0+r] f32 -> As[r][d] f16, packed 8 halfs per ds_write_b128
  const int r_own = t & 31;   // row this thread owns (staging, recheck, quant)
  const int ph = t >> 5;      // d-slice: ph*32 .. ph*32+31
  {
    const float* xb = x + (size_t)b * (EMB_DIM * HW) + hw0 + r_own;
#pragma unroll
    for (int jp = 0; jp < 4; ++jp) {
      const int d0 = ph * 32 + jp * 8;
      f16x8 v;
#pragma unroll
      for (int e = 0; e < 8; ++e)
        v[e] = (_Float16)xb[(size_t)(d0 + e) * HW];
      *(f16x8*)&As[r_own * LDA + d0] = v;
    }
  }
  __syncthreads();   // A tile staged

  uint t1[8], t2[8];
#pragma unroll
  for (int i = 0; i < 8; ++i) { t1[i] = 0u; t2[i] = 0u; }

#pragma unroll
  for (int c4 = 0; c4 < 4; ++c4) {
    f32x4 acc[2][4];
#pragma unroll
    for (int rt = 0; rt < 2; ++rt)
#pragma unroll
      for (int ct = 0; ct < 4; ++ct) acc[rt][ct] = (f32x4)0.f;

#pragma unroll
    for (int ks = 0; ks < 8; ++ks) {
      const int s = c4 * 8 + ks;          // compile-time after unroll
      const int cb = s & 1, nb = cb ^ 1;  // STATIC double-buffer indices
      if (s < 31) { LOADB(bb[nb], s + 1); }   // depth-1 prefetch, linear slabs

      const f16x8 a0 = *(const f16x8*)&As[( 0 + l15) * LDA + ks * 32 + q * 8];
      const f16x8 a1 = *(const f16x8*)&As[(16 + l15) * LDA + ks * 32 + q * 8];

      __builtin_amdgcn_s_setprio(1);
#pragma unroll
      for (int ct = 0; ct < 4; ++ct) {
        acc[0][ct] = __builtin_amdgcn_mfma_f32_16x16x32_f16(a0, bb[cb][ct], acc[0][ct], 0, 0, 0);
        acc[1][ct] = __builtin_amdgcn_mfma_f32_16x16x32_f16(a1, bb[cb][ct], acc[1][ct], 0, 0, 0);
      }
      __builtin_amdgcn_s_setprio(0);
    }

    // merge into per-(lane,slot) top-2 packed keys (score hi-bits | idx)
#pragma unroll
    for (int ct = 0; ct < 4; ++ct) {
      const uint idxv = (uint)(c4 * 256 + w4id * 64 + ct * 16 + l15);
#pragma unroll
      for (int rt = 0; rt < 2; ++rt)
#pragma unroll
        for (int r = 0; r < 4; ++r) {
          const float v = fmaxf(acc[rt][ct][r], 0.0f);
          const uint key = (__float_as_uint(v) & 0xFFFFFC00u) | idxv;
          const int slot = rt * 4 + r;
          t2[slot] = umed3(key, t1[slot], t2[slot]);
          t1[slot] = umax2(key, t1[slot]);
        }
    }
  }
#undef LOADB

  // ---- block-level per-row top-4 (reuse A LDS as key scratch: 32 rows x KSTR dwords) ----
  __syncthreads();   // all waves done reading As
  uint* keys = (uint*)As;
#pragma unroll
  for (int slot = 0; slot < 8; ++slot) {
    const int rt = slot >> 2, r = slot & 3;
    const int row = rt * 16 + q * 4 + r;
    const int col = w4id * 32 + l15 * 2;
    keys[row * KSTR + col] = t1[slot];
    keys[row * KSTR + col + 1] = t2[slot];
  }
  __syncthreads();
  {
    const int row = t >> 3, seg = t & 7;   // 8 threads per row, 16 keys each
    uint s1 = 0, s2 = 0;
#pragma unroll
    for (int i = 0; i < 4; ++i) {
      const int ii = (i + t) & 3;
      const uint4 k4 = *(const uint4*)&keys[row * KSTR + seg * 16 + ii * 4];
      const uint kk[4] = {k4.x, k4.y, k4.z, k4.w};
#pragma unroll
      for (int e = 0; e < 4; ++e) {
        s2 = umed3(kk[e], s1, s2);
        s1 = umax2(kk[e], s1);
      }
    }
    __syncthreads();
    keys[t * 2] = s1;
    keys[t * 2 + 1] = s2;
  }
  __syncthreads();
  if (t < 32) {
    uint c0 = 0, c1 = 0, c2 = 0, c3 = 0;
#pragma unroll
    for (int i = 0; i < 16; ++i) {
      const uint k = keys[t * 16 + i];
      const uint n0 = umin2(c0, k); c0 = umax2(c0, k);
      const uint n1 = umin2(c1, n0); c1 = umax2(c1, n0);
      const uint n2 = umin2(c2, n1); c2 = umax2(c2, n1);
      c3 = umax2(c3, n2);
    }
    uint4 o; o.x = c0; o.y = c1; o.z = c2; o.w = c3;
    cand_s[t] = o;
  }
  __syncthreads();   // cand ready; keys region free for red reuse

  // ---- fp64 recheck: thread covers (r_own, 32-d slice); x re-read from L3 ----
  double* red = (double*)As;   // 256 threads x 5 doubles = 10240 B
  {
    const uint4 ck = cand_s[r_own];
    const uint cv[4] = {ck.x, ck.y, ck.z, ck.w};
    const float* xr = x + (size_t)b * (EMB_DIM * HW) + hw0 + r_own;
    float xf[32];
#pragma unroll
    for (int i = 0; i < 32; ++i)
      xf[i] = xr[(size_t)(ph * 32 + i) * HW];
    double sxx_p = 0.0;
#pragma unroll
    for (int i = 0; i < 32; ++i) sxx_p = fma((double)xf[i], (double)xf[i], sxx_p);
#pragma unroll
    for (int j = 0; j < 4; ++j) {
      const int c = (int)(cv[j] & 1023u);
      const float* wr = w + (size_t)c * EMB_DIM + ph * 32;
      double s = 0.0;
#pragma unroll
      for (int k = 0; k < 8; ++k) {
        const float4 wv = *(const float4*)&wr[k * 4];
        s = fma((double)xf[k * 4 + 0], (double)wv.x, s);
        s = fma((double)xf[k * 4 + 1], (double)wv.y, s);
        s = fma((double)xf[k * 4 + 2], (double)wv.z, s);
        s = fma((double)xf[k * 4 + 3], (double)wv.w, s);
      }
      red[t * 5 + j] = s;
    }
    red[t * 5 + 4] = sxx_p;
  }
  __syncthreads();

  // ---- per-row decision (first 32 lanes), loss reduce, idx store ----
  if (t < 32) {
    const uint4 ck = cand_s[t];
    const uint cv[4] = {ck.x, ck.y, ck.z, ck.w};
    double sj[4] = {0.0, 0.0, 0.0, 0.0};
    double sxx = 0.0;
#pragma unroll
    for (int p = 0; p < 8; ++p) {
      const int base = (p * 32 + t) * 5;
      sj[0] += red[base + 0];
      sj[1] += red[base + 1];
      sj[2] += red[base + 2];
      sj[3] += red[base + 3];
      sxx   += red[base + 4];
    }
    double qbest = -1e300; int cw = 1 << 30;
#pragma unroll
    for (int j = 0; j < 4; ++j) {
      const int c = (int)(cv[j] & 1023u);
      const double qj = sj[j] * rinv[c];
      if (qj > qbest || (qj == qbest && c < cw)) { qbest = qj; cw = c; }
    }
    const double dmin = 2.0 - 2.0 * qbest / fmax(sqrt(sxx), 1e-12);
    out[IDX_OFF + blk * 32 + t] = (float)cw;
    cw_s[t] = cw;
    double v = dmin;
    v += __shfl_down(v, 16);
    v += __shfl_down(v, 8);
    v += __shfl_down(v, 4);
    v += __shfl_down(v, 2);
    v += __shfl_down(v, 1);
    if (t == 0)
      atomicAdd(out, (float)(1.25 * v / 16777216.0));
  }
  __syncthreads();

  // ---- quant: direct coalesced stores (half-wave-per-row, 128B segments per instr) ----
  {
    const int cw = cw_s[r_own];
    const float* wr = wn + (size_t)cw * EMB_DIM + ph * 32;
    float* qo = out + QUANT_OFF + (size_t)b * (EMB_DIM * HW) + hw0 + r_own;
#pragma unroll
    for (int k = 0; k < 8; ++k) {
      const float4 wv = *(const float4*)&wr[k * 4];
      qo[(size_t)(ph * 32 + k * 4 + 0) * HW] = wv.x;
      qo[(size_t)(ph * 32 + k * 4 + 1) * HW] = wv.y;
      qo[(size_t)(ph * 32 + k * 4 + 2) * HW] = wv.z;
      qo[(size_t)(ph * 32 + k * 4 + 3) * HW] = wv.w;
    }
  }
}

extern "C" void kernel_launch(void* const* d_in, const int* in_sizes, int n_in,
                              void* d_out, int out_size, void* d_ws, size_t ws_size,
                              hipStream_t stream) {
  const float* x = (const float*)d_in[0];   // [64,256,32,32]
  const float* w = (const float*)d_in[1];   // [1024,256]
  float* out = (float*)d_out;               // [1 + 16777216 + 65536] f32

  char* ws = (char*)d_ws;
  float*     wn   = (float*)ws;                                // 1 MB
  _Float16*  wh2  = (_Float16*)(ws + 1048576);                 // 512 KB (swizzled)
  double*    rinv = (double*)(ws + 1048576 + 524288);          // 8 KB

  hipMemsetAsync(d_out, 0, sizeof(float), stream);   // zero loss accumulator
  hipLaunchKernelGGL(k_norm_w, dim3(NUM_EMB), dim3(256), 0, stream, w, wn, wh2, rinv);
  hipLaunchKernelGGL(k_fused, dim3(N_ROWS / 32), dim3(256), 0, stream, x, wh2, w, wn, rinv, out);
}

// Round 7
// 201.154 us; speedup vs baseline: 1.3873x; 1.2512x over previous
//
#include <hip/hip_runtime.h>
#include <math.h>

#define NUM_EMB 1024
#define EMB_DIM 256
#define N_ROWS  65536
#define HW      1024
#define QUANT_OFF 1
#define IDX_OFF   (1 + 16777216)
#define LDA 264   // halfs per A-row: 528B stride -> clean b128 access, 2-way banks (free)
#define KSTR 132  // key-scratch row stride in dwords

typedef unsigned int uint;
typedef _Float16 f16x8 __attribute__((ext_vector_type(8)));
typedef float    f32x4 __attribute__((ext_vector_type(4)));

__device__ __forceinline__ uint umin2(uint a, uint b) { return a < b ? a : b; }
__device__ __forceinline__ uint umax2(uint a, uint b) { return a > b ? a : b; }

// median of 3 == 2nd-largest of 3; single VALU op on gfx9+
__device__ __forceinline__ uint umed3(uint a, uint b, uint c) {
  uint d;
  asm("v_med3_u32 %0, %1, %2, %3" : "=v"(d) : "v"(a), "v"(b), "v"(c));
  return d;
}

// ---- kernel 1: normalize codebook -> wn (f32), wh2 (f16, MFMA-B-swizzled), rinv (f64) ----
// wh2 halfs layout: [chunk(4)][ks(8)][q(4)][code-in-chunk(256)][e(8)], d = ks*32+q*8+e.
// Equivalently: slab s = chunk*8+ks at offset s*8192.
__global__ __launch_bounds__(256)
void k_norm_w(const float* __restrict__ w, float* __restrict__ wn,
              _Float16* __restrict__ wh2, double* __restrict__ rinv) {
  const int k = blockIdx.x, t = threadIdx.x;
  const float v = w[(size_t)k * EMB_DIM + t];
  double s = (double)v * (double)v;
  for (int o = 32; o; o >>= 1) s += __shfl_down(s, o);
  __shared__ double ps[4];
  if ((t & 63) == 0) ps[t >> 6] = s;
  __syncthreads();
  const double tot = ps[0] + ps[1] + ps[2] + ps[3];
  const float nv = v / fmaxf((float)sqrt(tot), 1e-12f);
  wn[(size_t)k * EMB_DIM + t] = nv;
  const int chunk = k >> 8, cc = k & 255;
  const int ks = t >> 5, q = (t >> 3) & 3, e = t & 7;
  wh2[(size_t)chunk * 65536 + ks * 8192 + q * 2048 + cc * 8 + e] = (_Float16)nv;
  if (t == 0) rinv[k] = 1.0 / fmax(sqrt(tot), 1e-12);
}

// ---- fused kernel: MFMA top-4 + fp64 recheck + loss + quant ----
// 2048 blocks x 256 thr, 32 rows/block (8 blocks/CU queued -> phase-skewed rotation).
// B streamed L2->VGPR with depth-1 double buffer (static cb = s&1 indexing);
// A in LDS; recheck re-reads x from L3; quant stores direct.
// launch_bounds (256,2): (256,4) capped the unified VGPR/AGPR budget at 128 ->
// allocator pinned arch-VGPRs at 64 and spilled ~100MB/dispatch (rounds 5-6).
__global__ __launch_bounds__(256, 2)
void k_fused(const float* __restrict__ x, const _Float16* __restrict__ wh2,
             const float* __restrict__ w, const float* __restrict__ wn,
             const double* __restrict__ rinv, float* __restrict__ out) {
  __shared__ __align__(16) _Float16 As[32 * LDA];   // 16896 B; reused: keys / red
  __shared__ uint4 cand_s[32];
  __shared__ int   cw_s[32];
  const int t = threadIdx.x;
  const int blk = blockIdx.x;
  const int b = blk >> 5;
  const int hw0 = (blk & 31) * 32;

  const int lane = t & 63;
  const int q = lane >> 4;
  const int l15 = lane & 15;
  const int w4id = t >> 6;

  // per-lane B element offsets (halfs) within a ks-slab of wh2
  const int bvo0 = q * 2048 + (w4id * 64 +  0 + l15) * 8;
  const int bvo1 = q * 2048 + (w4id * 64 + 16 + l15) * 8;
  const int bvo2 = q * 2048 + (w4id * 64 + 32 + l15) * 8;
  const int bvo3 = q * 2048 + (w4id * 64 + 48 + l15) * 8;

#define LOADB(buf, s)                                       \
  { const _Float16* ksb_ = wh2 + (size_t)(s) * 8192;        \
    buf[0] = *(const f16x8*)&ksb_[bvo0];                    \
    buf[1] = *(const f16x8*)&ksb_[bvo1];                    \
    buf[2] = *(const f16x8*)&ksb_[bvo2];                    \
    buf[3] = *(const f16x8*)&ksb_[bvo3]; }

  f16x8 bb[2][4];
  LOADB(bb[0], 0);   // prefetch first B step (overlaps A staging)

  // stage A: x[b, d, hw0+r] f32 -> As[r][d] f16, packed 8 halfs per ds_write_b128
  const int r_own = t & 31;   // row this thread owns (staging, recheck, quant)
  const int ph = t >> 5;      // d-slice: ph*32 .. ph*32+31
  {
    const float* xb = x + (size_t)b * (EMB_DIM * HW) + hw0 + r_own;
#pragma unroll
    for (int jp = 0; jp < 4; ++jp) {
      const int d0 = ph * 32 + jp * 8;
      f16x8 v;
#pragma unroll
      for (int e = 0; e < 8; ++e)
        v[e] = (_Float16)xb[(size_t)(d0 + e) * HW];
      *(f16x8*)&As[r_own * LDA + d0] = v;
    }
  }
  __syncthreads();   // A tile staged

  uint t1[8], t2[8];
#pragma unroll
  for (int i = 0; i < 8; ++i) { t1[i] = 0u; t2[i] = 0u; }

#pragma unroll
  for (int c4 = 0; c4 < 4; ++c4) {
    f32x4 acc[2][4];
#pragma unroll
    for (int rt = 0; rt < 2; ++rt)
#pragma unroll
      for (int ct = 0; ct < 4; ++ct) acc[rt][ct] = (f32x4)0.f;

#pragma unroll
    for (int ks = 0; ks < 8; ++ks) {
      const int s = c4 * 8 + ks;          // compile-time after unroll
      const int cb = s & 1, nb = cb ^ 1;  // STATIC double-buffer indices
      if (s < 31) { LOADB(bb[nb], s + 1); }   // depth-1 prefetch, linear slabs

      const f16x8 a0 = *(const f16x8*)&As[( 0 + l15) * LDA + ks * 32 + q * 8];
      const f16x8 a1 = *(const f16x8*)&As[(16 + l15) * LDA + ks * 32 + q * 8];

      __builtin_amdgcn_s_setprio(1);
#pragma unroll
      for (int ct = 0; ct < 4; ++ct) {
        acc[0][ct] = __builtin_amdgcn_mfma_f32_16x16x32_f16(a0, bb[cb][ct], acc[0][ct], 0, 0, 0);
        acc[1][ct] = __builtin_amdgcn_mfma_f32_16x16x32_f16(a1, bb[cb][ct], acc[1][ct], 0, 0, 0);
      }
      __builtin_amdgcn_s_setprio(0);
    }

    // merge into per-(lane,slot) top-2 packed keys (score hi-bits | idx)
#pragma unroll
    for (int ct = 0; ct < 4; ++ct) {
      const uint idxv = (uint)(c4 * 256 + w4id * 64 + ct * 16 + l15);
#pragma unroll
      for (int rt = 0; rt < 2; ++rt)
#pragma unroll
        for (int r = 0; r < 4; ++r) {
          const float v = fmaxf(acc[rt][ct][r], 0.0f);
          const uint key = (__float_as_uint(v) & 0xFFFFFC00u) | idxv;
          const int slot = rt * 4 + r;
          t2[slot] = umed3(key, t1[slot], t2[slot]);
          t1[slot] = umax2(key, t1[slot]);
        }
    }
  }
#undef LOADB

  // ---- block-level per-row top-4 (reuse A LDS as key scratch: 32 rows x KSTR dwords) ----
  __syncthreads();   // all waves done reading As
  uint* keys = (uint*)As;
#pragma unroll
  for (int slot = 0; slot < 8; ++slot) {
    const int rt = slot >> 2, r = slot & 3;
    const int row = rt * 16 + q * 4 + r;
    const int col = w4id * 32 + l15 * 2;
    keys[row * KSTR + col] = t1[slot];
    keys[row * KSTR + col + 1] = t2[slot];
  }
  __syncthreads();
  {
    const int row = t >> 3, seg = t & 7;   // 8 threads per row, 16 keys each
    uint s1 = 0, s2 = 0;
#pragma unroll
    for (int i = 0; i < 4; ++i) {
      const int ii = (i + t) & 3;
      const uint4 k4 = *(const uint4*)&keys[row * KSTR + seg * 16 + ii * 4];
      const uint kk[4] = {k4.x, k4.y, k4.z, k4.w};
#pragma unroll
      for (int e = 0; e < 4; ++e) {
        s2 = umed3(kk[e], s1, s2);
        s1 = umax2(kk[e], s1);
      }
    }
    __syncthreads();
    keys[t * 2] = s1;
    keys[t * 2 + 1] = s2;
  }
  __syncthreads();
  if (t < 32) {
    uint c0 = 0, c1 = 0, c2 = 0, c3 = 0;
#pragma unroll
    for (int i = 0; i < 16; ++i) {
      const uint k = keys[t * 16 + i];
      const uint n0 = umin2(c0, k); c0 = umax2(c0, k);
      const uint n1 = umin2(c1, n0); c1 = umax2(c1, n0);
      const uint n2 = umin2(c2, n1); c2 = umax2(c2, n1);
      c3 = umax2(c3, n2);
    }
    uint4 o; o.x = c0; o.y = c1; o.z = c2; o.w = c3;
    cand_s[t] = o;
  }
  __syncthreads();   // cand ready; keys region free for red reuse

  // ---- fp64 recheck: thread covers (r_own, 32-d slice); x re-read from L3 ----
  double* red = (double*)As;   // 256 threads x 5 doubles = 10240 B
  {
    const uint4 ck = cand_s[r_own];
    const uint cv[4] = {ck.x, ck.y, ck.z, ck.w};
    const float* xr = x + (size_t)b * (EMB_DIM * HW) + hw0 + r_own;
    float xf[32];
#pragma unroll
    for (int i = 0; i < 32; ++i)
      xf[i] = xr[(size_t)(ph * 32 + i) * HW];
    double sxx_p = 0.0;
#pragma unroll
    for (int i = 0; i < 32; ++i) sxx_p = fma((double)xf[i], (double)xf[i], sxx_p);
#pragma unroll
    for (int j = 0; j < 4; ++j) {
      const int c = (int)(cv[j] & 1023u);
      const float* wr = w + (size_t)c * EMB_DIM + ph * 32;
      double s = 0.0;
#pragma unroll
      for (int k = 0; k < 8; ++k) {
        const float4 wv = *(const float4*)&wr[k * 4];
        s = fma((double)xf[k * 4 + 0], (double)wv.x, s);
        s = fma((double)xf[k * 4 + 1], (double)wv.y, s);
        s = fma((double)xf[k * 4 + 2], (double)wv.z, s);
        s = fma((double)xf[k * 4 + 3], (double)wv.w, s);
      }
      red[t * 5 + j] = s;
    }
    red[t * 5 + 4] = sxx_p;
  }
  __syncthreads();

  // ---- per-row decision (first 32 lanes), loss reduce, idx store ----
  if (t < 32) {
    const uint4 ck = cand_s[t];
    const uint cv[4] = {ck.x, ck.y, ck.z, ck.w};
    double sj[4] = {0.0, 0.0, 0.0, 0.0};
    double sxx = 0.0;
#pragma unroll
    for (int p = 0; p < 8; ++p) {
      const int base = (p * 32 + t) * 5;
      sj[0] += red[base + 0];
      sj[1] += red[base + 1];
      sj[2] += red[base + 2];
      sj[3] += red[base + 3];
      sxx   += red[base + 4];
    }
    double qbest = -1e300; int cw = 1 << 30;
#pragma unroll
    for (int j = 0; j < 4; ++j) {
      const int c = (int)(cv[j] & 1023u);
      const double qj = sj[j] * rinv[c];
      if (qj > qbest || (qj == qbest && c < cw)) { qbest = qj; cw = c; }
    }
    const double dmin = 2.0 - 2.0 * qbest / fmax(sqrt(sxx), 1e-12);
    out[IDX_OFF + blk * 32 + t] = (float)cw;
    cw_s[t] = cw;
    double v = dmin;
    v += __shfl_down(v, 16);
    v += __shfl_down(v, 8);
    v += __shfl_down(v, 4);
    v += __shfl_down(v, 2);
    v += __shfl_down(v, 1);
    if (t == 0)
      atomicAdd(out, (float)(1.25 * v / 16777216.0));
  }
  __syncthreads();

  // ---- quant: direct coalesced stores (half-wave-per-row, 128B segments per instr) ----
  {
    const int cw = cw_s[r_own];
    const float* wr = wn + (size_t)cw * EMB_DIM + ph * 32;
    float* qo = out + QUANT_OFF + (size_t)b * (EMB_DIM * HW) + hw0 + r_own;
#pragma unroll
    for (int k = 0; k < 8; ++k) {
      const float4 wv = *(const float4*)&wr[k * 4];
      qo[(size_t)(ph * 32 + k * 4 + 0) * HW] = wv.x;
      qo[(size_t)(ph * 32 + k * 4 + 1) * HW] = wv.y;
      qo[(size_t)(ph * 32 + k * 4 + 2) * HW] = wv.z;
      qo[(size_t)(ph * 32 + k * 4 + 3) * HW] = wv.w;
    }
  }
}

extern "C" void kernel_launch(void* const* d_in, const int* in_sizes, int n_in,
                              void* d_out, int out_size, void* d_ws, size_t ws_size,
                              hipStream_t stream) {
  const float* x = (const float*)d_in[0];   // [64,256,32,32]
  const float* w = (const float*)d_in[1];   // [1024,256]
  float* out = (float*)d_out;               // [1 + 16777216 + 65536] f32

  char* ws = (char*)d_ws;
  float*     wn   = (float*)ws;                                // 1 MB
  _Float16*  wh2  = (_Float16*)(ws + 1048576);                 // 512 KB (swizzled)
  double*    rinv = (double*)(ws + 1048576 + 524288);          // 8 KB

  hipMemsetAsync(d_out, 0, sizeof(float), stream);   // zero loss accumulator
  hipLaunchKernelGGL(k_norm_w, dim3(NUM_EMB), dim3(256), 0, stream, w, wn, wh2, rinv);
  hipLaunchKernelGGL(k_fused, dim3(N_ROWS / 32), dim3(256), 0, stream, x, wh2, w, wn, rinv, out);
}